// Round 5
// baseline (1353.937 us; speedup 1.0000x reference)
//
#include <hip/hip_runtime.h>

#define T_TOK 4096
#define H_DIM 2048
#define I_DIM 5632
#define NE 8

typedef _Float16 f16;
typedef _Float16 f16x8 __attribute__((ext_vector_type(8)));
typedef _Float16 f16x4 __attribute__((ext_vector_type(4)));
typedef float f32x4 __attribute__((ext_vector_type(4)));

// ---- workspace layout (byte offsets) ----
#define OFF_META   0                         // counts[8] | offs[8] | cursor[8]
#define OFF_BTOK   256
#define OFF_BW     (256 + 32768)
#define OFF_RE     (256 + 2 * 32768)
#define OFF_RW     (256 + 3 * 32768)
#define OFF_HSB    (256 + 4 * 32768)
#define OFF_HB     (OFF_HSB + (size_t)T_TOK * H_DIM * 2)

typedef const __attribute__((address_space(1))) unsigned int guint;
typedef __attribute__((address_space(3))) unsigned int luint;

#define WAITLG0()  asm volatile("s_waitcnt lgkmcnt(0)" ::: "memory")

// 8-slot (16B) XOR swizzle within a 128-byte LDS row: conflict-free reads (verified R3/R4: 0 conflicts)
__device__ __forceinline__ int swzk(int r, int bir) {
    return (bir & 15) | ((((bir >> 4) ^ r) & 7) << 4);
}

__device__ __forceinline__ f16x4 cvt4(float4 v) {
    f16x4 t; t[0] = (f16)v.x; t[1] = (f16)v.y; t[2] = (f16)v.z; t[3] = (f16)v.w; return t;
}

// ---------------- hs f32 -> f16 ----------------
__global__ void cvt_hs_kernel(const float* __restrict__ hs, f16* __restrict__ hsb) {
    size_t i = ((size_t)blockIdx.x * 256 + threadIdx.x) * 8;
    float4 a = *(const float4*)(hs + i);
    float4 b = *(const float4*)(hs + i + 4);
    f16x8 v;
    v[0] = (f16)a.x; v[1] = (f16)a.y; v[2] = (f16)a.z; v[3] = (f16)a.w;
    v[4] = (f16)b.x; v[5] = (f16)b.y; v[6] = (f16)b.z; v[7] = (f16)b.w;
    *(f16x8*)(hsb + i) = v;
}

// ---------------- gating ----------------
__global__ void gate_kernel(const float* __restrict__ hs, const float* __restrict__ gw,
                            int* __restrict__ re, float* __restrict__ rw,
                            int* __restrict__ counts) {
    int lane = threadIdx.x & 63;
    int t = blockIdx.x * 4 + (threadIdx.x >> 6);
    float acc[NE];
#pragma unroll
    for (int e = 0; e < NE; ++e) acc[e] = 0.f;
    const float* x = hs + (size_t)t * H_DIM;
    for (int i = lane; i < H_DIM; i += 64) {
        float xv = x[i];
#pragma unroll
        for (int e = 0; e < NE; ++e) acc[e] += xv * gw[e * H_DIM + i];
    }
#pragma unroll
    for (int e = 0; e < NE; ++e)
        for (int off = 32; off > 0; off >>= 1) acc[e] += __shfl_xor(acc[e], off);
    if (lane == 0) {
        int i1 = 0; float l1 = acc[0];
#pragma unroll
        for (int e = 1; e < NE; ++e) if (acc[e] > l1) { l1 = acc[e]; i1 = e; }
        int i2 = -1; float l2 = -1e30f;
#pragma unroll
        for (int e = 0; e < NE; ++e) if (e != i1 && acc[e] > l2) { l2 = acc[e]; i2 = e; }
        float aa = __expf(l2 - l1);
        float s = 1.f / (1.f + aa);
        re[t * 2] = i1; re[t * 2 + 1] = i2;
        rw[t * 2] = s;  rw[t * 2 + 1] = aa * s;
        atomicAdd(&counts[i1], 1);
        atomicAdd(&counts[i2], 1);
    }
}

__global__ void scan_kernel(int* __restrict__ meta) {
    if (threadIdx.x == 0) {
        int s = 0;
        for (int e = 0; e < NE; ++e) { meta[8 + e] = s; meta[16 + e] = s; s += meta[e]; }
    }
}

__global__ void place_kernel(const int* __restrict__ re, const float* __restrict__ rw,
                             int* __restrict__ cursor, int* __restrict__ btok,
                             float* __restrict__ bwv) {
    int t = blockIdx.x * 256 + threadIdx.x;
    if (t >= T_TOK) return;
#pragma unroll
    for (int s = 0; s < 2; ++s) {
        int e = re[t * 2 + s];
        int p = atomicAdd(&cursor[e], 1);
        btok[p] = t;
        bwv[p] = rw[t * 2 + s];
    }
}

// Panel-pinned XCD decode (BM=256 -> 16 by-blocks per panel): panel P = sg*8 + (id&7)
// stays on XCD id%8; the 16 by-blocks of one panel are contiguous ids on that XCD.
__device__ __forceinline__ void decode_panel(int id, int npx, int e_arg,
                                             int& e, int& bx, int& by) {
    int sg  = id >> 7;          // super-group: 8 panels x 16 by = 128 blocks
    int rem = id & 127;
    by = rem >> 3;
    int P = sg * 8 + (rem & 7);
    if (e_arg >= 0) { e = e_arg; bx = P; }
    else            { e = P / npx; bx = P % npx; }
}

// ---------------- GEMM1: h = silu(X@Wg^T) * (X@Wu^T) ----------------
// BM=256 tokens x 64 g-cols + 64 u-cols, BK=64, 512 thr / 8 waves (4m x 2n),
// wave = 64 rows x (32 g + 32 u): 8 ds_reads feed 16 MFMAs (rho=0.5).
// A: global_load_lds double-buffered (pre-swizzled source, linear dest);
// B: f32->f16 reg-staged, single LDS buffer; raw barriers (no vmcnt(0) drain of prefetch).
__global__ __launch_bounds__(512, 4) void gemm1_kernel(
    const float* __restrict__ w13, const f16* __restrict__ hsb, f16* __restrict__ hb,
    const int* __restrict__ counts, const int* __restrict__ offs,
    const int* __restrict__ btok, int e_arg, int global_h)
{
    int e, bx, by;
    decode_panel(blockIdx.x, 88, e_arg, e, bx, by);
    const int n_e = counts[e];
    if (by * 256 >= n_e) return;
    const int boff = offs[e];
    const float* We = w13 + (size_t)e * (2 * I_DIM) * H_DIM;

    const int tid = threadIdx.x;
    const int lane = tid & 63;
    const int wid = tid >> 6;
    const int wm = wid >> 1;            // 0..3
    const int wn = wid & 1;             // 0..1

    __shared__ f16 As[2][256 * 64];     // 32 KB per buffer (rows of 128B, swizzled content)
    __shared__ f16 Bg[64 * 64];         // 8 KB
    __shared__ f16 Bu[64 * 64];         // 8 KB
    char* AsB = (char*)As; char* BgB = (char*)Bg; char* BuB = (char*)Bu;

    // A via global_load_lds: 2048 chunks of 16B; chunk c = i*512+tid -> row c>>3, pos c&7.
    // LDS pos p of row r holds global k-slot p ^ (r&7); dest byte = c*16 (linear in lane).
    const f16* gA[4];
    int adst[4];
#pragma unroll
    for (int i = 0; i < 4; ++i) {
        int c = i * 512 + tid;
        int r = c >> 3;
        int idx = by * 256 + r;
        idx = idx < n_e ? idx : n_e - 1;
        int tok = btok[boff + idx];
        int sg = (c & 7) ^ (r & 7);
        gA[i] = hsb + (size_t)tok * H_DIM + sg * 8;
        adst[i] = c * 16;
    }
    // B: per matrix 2 float4/thread. chunk c = j*512+tid: row c>>4 (0..63), quad c&15
    const float* gBg[2]; const float* gBu[2];
    int bwadr[2];
#pragma unroll
    for (int j = 0; j < 2; ++j) {
        int c = j * 512 + tid;
        int r = c >> 4;
        int k4 = c & 15;
        gBg[j] = We + (size_t)(bx * 64 + r) * H_DIM + k4 * 4;
        gBu[j] = We + (size_t)(I_DIM + bx * 64 + r) * H_DIM + k4 * 4;
        bwadr[j] = r * 128 + swzk(r, k4 * 8);
    }

    f32x4 accg[4][2], accu[4][2];
#pragma unroll
    for (int m = 0; m < 4; ++m)
#pragma unroll
        for (int n = 0; n < 2; ++n) { accg[m][n] = (f32x4)0.f; accu[m][n] = (f32x4)0.f; }

    const int NT = H_DIM / 64;   // 32

    // prologue: issue A[0] DMA + load B[0] regs
    float4 gR[2], uR[2];
#pragma unroll
    for (int i = 0; i < 4; ++i)
        __builtin_amdgcn_global_load_lds((guint*)(gA[i]), (luint*)(AsB + adst[i]), 16, 0, 0);
#pragma unroll
    for (int j = 0; j < 2; ++j) { gR[j] = *(const float4*)gBg[j]; uR[j] = *(const float4*)gBu[j]; }

    int cur = 0;
#pragma unroll 1
    for (int kt = 0; kt < NT; ++kt) {
        WAITLG0();
        __builtin_amdgcn_s_barrier();               // #1: LDS_B + A-buf[cur^1] free
        // stage B[kt] (compiler auto-waits vmcnt(0): B[kt] newest => A[kt] also landed)
#pragma unroll
        for (int j = 0; j < 2; ++j) {
            *(f16x4*)(BgB + bwadr[j]) = cvt4(gR[j]);
            *(f16x4*)(BuB + bwadr[j]) = cvt4(uR[j]);
        }
        if (kt + 1 < NT) {
            int k0 = (kt + 1) * 64;
#pragma unroll
            for (int i = 0; i < 4; ++i)
                __builtin_amdgcn_global_load_lds((guint*)(gA[i] + k0),
                    (luint*)(AsB + (cur ^ 1) * 32768 + adst[i]), 16, 0, 0);
        }
        WAITLG0();
        __builtin_amdgcn_s_barrier();               // #2: stage visible; A[kt] landed for all waves
        if (kt + 1 < NT) {
            int k0 = (kt + 1) * 64;
#pragma unroll
            for (int j = 0; j < 2; ++j) {
                gR[j] = *(const float4*)(gBg[j] + k0);
                uR[j] = *(const float4*)(gBu[j] + k0);
            }
        }
        const char* Ab = AsB + cur * 32768;
#pragma unroll
        for (int kh = 0; kh < 2; ++kh) {
            f16x8 a[4], bg[2], bu[2];
            const int kb = kh * 64 + (lane >> 4) * 16;
#pragma unroll
            for (int m = 0; m < 4; ++m) {
                int r = wm * 64 + m * 16 + (lane & 15);
                a[m] = *(const f16x8*)(Ab + r * 128 + swzk(r, kb));
            }
#pragma unroll
            for (int n = 0; n < 2; ++n) {
                int r = wn * 32 + n * 16 + (lane & 15);
                bg[n] = *(const f16x8*)(BgB + r * 128 + swzk(r, kb));
                bu[n] = *(const f16x8*)(BuB + r * 128 + swzk(r, kb));
            }
#pragma unroll
            for (int m = 0; m < 4; ++m)
#pragma unroll
                for (int n = 0; n < 2; ++n) {
                    accg[m][n] = __builtin_amdgcn_mfma_f32_16x16x32_f16(a[m], bg[n], accg[m][n], 0, 0, 0);
                    accu[m][n] = __builtin_amdgcn_mfma_f32_16x16x32_f16(a[m], bu[n], accu[m][n], 0, 0, 0);
                }
        }
        cur ^= 1;
    }

    // epilogue: silu(g)*u -> f16 h
    const int hbase = (global_h ? boff : 0) + by * 256;
#pragma unroll
    for (int m = 0; m < 4; ++m) {
        int rl0 = wm * 64 + m * 16 + ((lane >> 4) << 2);
#pragma unroll
        for (int r = 0; r < 4; ++r) {
            int rl = rl0 + r;
            if (by * 256 + rl < n_e) {
#pragma unroll
                for (int n = 0; n < 2; ++n) {
                    float g = accg[m][n][r];
                    float u = accu[m][n][r];
                    float h = g / (1.f + __expf(-g)) * u;
                    hb[(size_t)(hbase + rl) * I_DIM + bx * 64 + wn * 32 + n * 16 + (lane & 15)] = (f16)h;
                }
            }
        }
    }
}

// ---------------- GEMM2: out[tok] += w * (h @ w2^T) ----------------
// BM=256 x BN=128, BK=64, 512 thr / 8 waves (4m x 2n), wave 64x64 (rho=0.5).
__global__ __launch_bounds__(512, 4) void gemm2_kernel(
    const float* __restrict__ w2, const f16* __restrict__ hb, float* __restrict__ out,
    const int* __restrict__ counts, const int* __restrict__ offs,
    const int* __restrict__ btok, const float* __restrict__ bwv, int e_arg, int global_h)
{
    int e, bx, by;
    decode_panel(blockIdx.x, 16, e_arg, e, bx, by);
    const int n_e = counts[e];
    if (by * 256 >= n_e) return;
    const int boff = offs[e];
    const float* We = w2 + (size_t)e * H_DIM * I_DIM;

    const int tid = threadIdx.x;
    const int lane = tid & 63;
    const int wid = tid >> 6;
    const int wm = wid >> 1;
    const int wn = wid & 1;

    __shared__ f16 As[2][256 * 64];    // 32 KB per buffer
    __shared__ f16 Bs[128 * 64];       // 16 KB
    char* AsB = (char*)As; char* BsB = (char*)Bs;

    const int hbase = (global_h ? boff : 0) + by * 256;
    const f16* gA[4];
    int adst[4];
#pragma unroll
    for (int i = 0; i < 4; ++i) {
        int c = i * 512 + tid;
        int r = c >> 3;
        int sg = (c & 7) ^ (r & 7);
        gA[i] = hb + (size_t)(hbase + r) * I_DIM + sg * 8;
        adst[i] = c * 16;
    }
    const float* gB[4];
    int bwadr[4];
#pragma unroll
    for (int j = 0; j < 4; ++j) {
        int c = j * 512 + tid;
        int r = c >> 4;          // 0..127
        int k4 = c & 15;
        gB[j] = We + (size_t)(bx * 128 + r) * I_DIM + k4 * 4;
        bwadr[j] = r * 128 + swzk(r, k4 * 8);
    }

    f32x4 acc[4][4];
#pragma unroll
    for (int m = 0; m < 4; ++m)
#pragma unroll
        for (int n = 0; n < 4; ++n) acc[m][n] = (f32x4)0.f;

    const int NT = I_DIM / 64;   // 88

    float4 bR[4];
#pragma unroll
    for (int i = 0; i < 4; ++i)
        __builtin_amdgcn_global_load_lds((guint*)(gA[i]), (luint*)(AsB + adst[i]), 16, 0, 0);
#pragma unroll
    for (int j = 0; j < 4; ++j) bR[j] = *(const float4*)gB[j];

    int cur = 0;
#pragma unroll 1
    for (int kt = 0; kt < NT; ++kt) {
        WAITLG0();
        __builtin_amdgcn_s_barrier();               // #1
#pragma unroll
        for (int j = 0; j < 4; ++j) *(f16x4*)(BsB + bwadr[j]) = cvt4(bR[j]);
        if (kt + 1 < NT) {
            int k0 = (kt + 1) * 64;
#pragma unroll
            for (int i = 0; i < 4; ++i)
                __builtin_amdgcn_global_load_lds((guint*)(gA[i] + k0),
                    (luint*)(AsB + (cur ^ 1) * 32768 + adst[i]), 16, 0, 0);
        }
        WAITLG0();
        __builtin_amdgcn_s_barrier();               // #2
        if (kt + 1 < NT) {
            int k0 = (kt + 1) * 64;
#pragma unroll
            for (int j = 0; j < 4; ++j) bR[j] = *(const float4*)(gB[j] + k0);
        }
        const char* Ab = AsB + cur * 32768;
#pragma unroll
        for (int kh = 0; kh < 2; ++kh) {
            f16x8 a[4], b[4];
            const int kb = kh * 64 + (lane >> 4) * 16;
#pragma unroll
            for (int m = 0; m < 4; ++m) {
                int r = wm * 64 + m * 16 + (lane & 15);
                a[m] = *(const f16x8*)(Ab + r * 128 + swzk(r, kb));
            }
#pragma unroll
            for (int n = 0; n < 4; ++n) {
                int r = wn * 64 + n * 16 + (lane & 15);
                b[n] = *(const f16x8*)(BsB + r * 128 + swzk(r, kb));
            }
#pragma unroll
            for (int m = 0; m < 4; ++m)
#pragma unroll
                for (int n = 0; n < 4; ++n)
                    acc[m][n] = __builtin_amdgcn_mfma_f32_16x16x32_f16(a[m], b[n], acc[m][n], 0, 0, 0);
        }
        cur ^= 1;
    }

    // epilogue: weighted scatter-add
#pragma unroll
    for (int m = 0; m < 4; ++m) {
        int rl0 = wm * 64 + m * 16 + ((lane >> 4) << 2);
#pragma unroll
        for (int r = 0; r < 4; ++r) {
            int rl = rl0 + r;
            if (by * 256 + rl < n_e) {
                int p = boff + by * 256 + rl;
                int tok = btok[p];
                float w = bwv[p];
#pragma unroll
                for (int n = 0; n < 4; ++n)
                    atomicAdd(&out[(size_t)tok * H_DIM + bx * 128 + wn * 64 + n * 16 + (lane & 15)],
                              w * acc[m][n][r]);
            }
        }
    }
}

extern "C" void kernel_launch(void* const* d_in, const int* in_sizes, int n_in,
                              void* d_out, int out_size, void* d_ws, size_t ws_size,
                              hipStream_t stream) {
    const float* hs  = (const float*)d_in[0];
    const float* gw  = (const float*)d_in[1];
    const float* w13 = (const float*)d_in[2];
    const float* w2  = (const float*)d_in[3];
    float* out = (float*)d_out;

    char* ws = (char*)d_ws;
    int*   meta = (int*)(ws + OFF_META);
    int*   btok = (int*)(ws + OFF_BTOK);
    float* bwv  = (float*)(ws + OFF_BW);
    int*   re   = (int*)(ws + OFF_RE);
    float* rw   = (float*)(ws + OFF_RW);
    f16*   hsb  = (f16*)(ws + OFF_HSB);
    f16*   hb   = (f16*)(ws + OFF_HB);

    hipMemsetAsync(d_out, 0, (size_t)T_TOK * H_DIM * 4, stream);
    hipMemsetAsync(meta, 0, 256, stream);

    cvt_hs_kernel<<<(T_TOK * H_DIM) / (256 * 8), 256, 0, stream>>>(hs, hsb);
    gate_kernel<<<T_TOK / 4, 256, 0, stream>>>(hs, gw, re, rw, meta);
    scan_kernel<<<1, 64, 0, stream>>>(meta);
    place_kernel<<<T_TOK / 256, 256, 0, stream>>>(re, rw, meta + 16, btok, bwv);

    size_t need_allpairs = OFF_HB + (size_t)(2 * T_TOK + 256) * I_DIM * 2;
    if (ws_size >= need_allpairs) {
        // panels: gemm1 = 8e*88bx = 704, gemm2 = 8e*16bx = 128; 16 by-blocks per panel
        gemm1_kernel<<<704 * 16, 512, 0, stream>>>(w13, hsb, hb, meta, meta + 8, btok, -1, 1);
        gemm2_kernel<<<128 * 16, 512, 0, stream>>>(w2, hb, out, meta, meta + 8, btok, bwv, -1, 1);
    } else {
        for (int e = 0; e < NE; ++e) {
            gemm1_kernel<<<88 * 16, 512, 0, stream>>>(w13, hsb, hb, meta, meta + 8, btok, e, 0);
            gemm2_kernel<<<16 * 16, 512, 0, stream>>>(w2, hb, out, meta, meta + 8, btok, bwv, e, 0);
        }
    }
}